// Round 7
// baseline (189.371 us; speedup 1.0000x reference)
//
#include <hip/hip_runtime.h>
#include <hip/hip_bf16.h>

typedef short short8 __attribute__((ext_vector_type(8)));
typedef float f32x4 __attribute__((ext_vector_type(4)));
typedef unsigned short u16x4 __attribute__((ext_vector_type(4)));

#define D_ 256
#define K_ 1024
#define HW_ 1024
#define NROWS_ 32768
#define QELEMS 8388608  // 32*256*32*32

static __device__ __forceinline__ unsigned short to_bf16(float v) {
    __hip_bfloat16 h = __float2bfloat16(v);
    return *(unsigned short*)&h;
}

// ---------------- prep: emb -> bf16 codebook ebf[k][d], enorm[k]=sum e^2, zero counts/loss
__global__ __launch_bounds__(256) void vq_prep(const float* __restrict__ emb,
    unsigned short* __restrict__ ebf, float* __restrict__ enorm,
    int* __restrict__ counts, double* __restrict__ loss_acc)
{
    int k = blockIdx.x, t = threadIdx.x;           // k in [0,1024), t in [0,256)
    float v = emb[k * D_ + t];
    ebf[k * D_ + t] = to_bf16(v);
    float s = v * v;
    for (int o = 32; o > 0; o >>= 1) s += __shfl_down(s, o);
    __shared__ float ws4[4];
    if ((t & 63) == 0) ws4[t >> 6] = s;
    __syncthreads();
    if (t == 0) enorm[k] = ws4[0] + ws4[1] + ws4[2] + ws4[3];
    if (k < 4) counts[k * 256 + t] = 0;
    if (k == 0 && t == 0) *loss_acc = 0.0;
}

// ---------------- main: 64 rows/block, 8 waves, bf16 MFMA vs all 1024 codes, top-1, fused loss
__global__ __launch_bounds__(512, 4) void vq_main(
    const float* __restrict__ x,
    const unsigned short* __restrict__ ebf, const float* __restrict__ enorm,
    int* __restrict__ idx, int* __restrict__ counts, double* __restrict__ loss_acc)
{
    __shared__ unsigned short xs[64 * 256];   // 32KB, XOR-swizzled row-major bf16
    __shared__ float xn[64][33];              // per-row |x|^2 partials
    __shared__ float rminv[64][2];
    __shared__ int   rmini[64][2];

    const int t = threadIdx.x;
    const int n0 = blockIdx.x * 64;
    const int b = n0 >> 10;
    const int hw0 = n0 & 1023;
    const float* xbase = x + (size_t)b * (D_ * HW_) + hw0;

    // ---- stage x -> bf16 LDS: float4 loads along hw, 4x4 register transpose, b64 writes
    {
        const int rt = t & 15;          // row tile (rows 4rt..4rt+3)
        const int dg = t >> 4;          // 0..31
        const int r0 = rt * 4;
        float xp[4] = {0.f, 0.f, 0.f, 0.f};
#pragma unroll
        for (int m = 0; m < 2; ++m) {
            int d0 = (dg + 32 * m) * 4;
            f32x4 c[4];
#pragma unroll
            for (int q = 0; q < 4; ++q)
                c[q] = *(const f32x4*)(xbase + (size_t)(d0 + q) * HW_ + r0);
            // c[q][i] = x[d0+q][row r0+i]
#pragma unroll
            for (int i = 0; i < 4; ++i) {
                u16x4 pk;
                pk[0] = to_bf16(c[0][i]); pk[1] = to_bf16(c[1][i]);
                pk[2] = to_bf16(c[2][i]); pk[3] = to_bf16(c[3][i]);
                xp[i] = fmaf(c[0][i], c[0][i], xp[i]);
                xp[i] = fmaf(c[1][i], c[1][i], xp[i]);
                xp[i] = fmaf(c[2][i], c[2][i], xp[i]);
                xp[i] = fmaf(c[3][i], c[3][i], xp[i]);
                int r = r0 + i;
                int byte = (r * 512 + d0 * 2) ^ ((r & 7) << 4);
                *(u16x4*)((char*)xs + byte) = pk;
            }
        }
#pragma unroll
        for (int i = 0; i < 4; ++i) xn[r0 + i][dg] = xp[i];
    }
    __syncthreads();

    const int lane = t & 63;
    const int w = t >> 6;          // wave 0..7
    const int rq = w & 3;          // row quarter (16 rows)
    const int ch = w >> 2;         // code half
    const int col = lane & 15;
    const int kg = lane >> 4;      // k-group 0..3

    // ---- A fragments for this wave's 16 rows (held in registers for whole kernel)
    short8 areg[8];
    {
        int row = rq * 16 + col;
        int rowb = row * 512;
        int sw = (row & 7) << 4;
#pragma unroll
        for (int dc = 0; dc < 8; ++dc) {
            int byte = (rowb + dc * 64 + kg * 16) ^ sw;
            areg[dc] = *(const short8*)((const char*)xs + byte);
        }
    }

    float v1[4]; int i1[4];
#pragma unroll
    for (int r = 0; r < 4; ++r) { v1[r] = 3.4e38f; i1[r] = 0x7fffffff; }

    for (int cc = 0; cc < 16; ++cc) {
        const int cbase = cc * 64 + ch * 32;
        f32x4 acc0 = {0.f, 0.f, 0.f, 0.f};
        f32x4 acc1 = {0.f, 0.f, 0.f, 0.f};
#pragma unroll
        for (int dc = 0; dc < 8; ++dc) {
            short8 b0 = *(const short8*)(ebf + ((size_t)(cbase + col) << 8) + dc * 32 + kg * 8);
            short8 b1 = *(const short8*)(ebf + ((size_t)(cbase + 16 + col) << 8) + dc * 32 + kg * 8);
            acc0 = __builtin_amdgcn_mfma_f32_16x16x32_bf16(areg[dc], b0, acc0, 0, 0, 0);
            acc1 = __builtin_amdgcn_mfma_f32_16x16x32_bf16(areg[dc], b1, acc1, 0, 0, 0);
        }
        // dist = enorm - 2*dot ; C/D map: row=(lane>>4)*4+reg, col=lane&15
        {
            int code = cbase + col;
            float bn = enorm[code];
#pragma unroll
            for (int r = 0; r < 4; ++r) {
                float dv = fmaf(-2.f, acc0[r], bn);
                if (dv < v1[r]) { v1[r] = dv; i1[r] = code; }
            }
        }
        {
            int code = cbase + 16 + col;
            float bn = enorm[code];
#pragma unroll
            for (int r = 0; r < 4; ++r) {
                float dv = fmaf(-2.f, acc1[r], bn);
                if (dv < v1[r]) { v1[r] = dv; i1[r] = code; }
            }
        }
    }

    // ---- butterfly min over the 16 cols (lane bits 0-3), tie -> lower index
#pragma unroll
    for (int mask = 1; mask < 16; mask <<= 1) {
#pragma unroll
        for (int r = 0; r < 4; ++r) {
            float ov = __shfl_xor(v1[r], mask);
            int oi = __shfl_xor(i1[r], mask);
            if (ov < v1[r] || (ov == v1[r] && oi < i1[r])) { v1[r] = ov; i1[r] = oi; }
        }
    }
    if (col == 0) {
#pragma unroll
        for (int r = 0; r < 4; ++r) {
            int row = rq * 16 + kg * 4 + r;
            rminv[row][ch] = v1[r];
            rmini[row][ch] = i1[r];
        }
    }
    __syncthreads();

    // ---- finalize (wave 0): pick across code halves, idx/counts/loss
    if (t < 64) {
        float av = rminv[t][0], bv = rminv[t][1];
        int ai = rmini[t][0], bi = rmini[t][1];
        float dmin; int best;
        if (bv < av || (bv == av && bi < ai)) { dmin = bv; best = bi; }
        else { dmin = av; best = ai; }
        idx[n0 + t] = best;
        atomicAdd(&counts[best], 1);
        float s = 0.f;
#pragma unroll 8
        for (int g = 0; g < 32; ++g) s += xn[t][g];
        float lrow = dmin + s;     // |x-e|^2 = (|e|^2 - 2x.e) + |x|^2
        for (int o = 32; o > 0; o >>= 1) lrow += __shfl_down(lrow, o);
        if (t == 0) atomicAdd(loss_acc, (double)lrow);
    }
}

// ---------------- scatter quantized (BCHW): out[b][d][hw] = emb[idx[b*1024+hw]][d]
__global__ __launch_bounds__(256) void vq_scatter(const float* __restrict__ emb,
    const int* __restrict__ idx, float* __restrict__ outq)
{
    size_t m = (size_t)blockIdx.x * 256 + threadIdx.x;
    int hw = (int)(m & 1023);
    int d = (int)((m >> 10) & 255);
    int b = (int)(m >> 18);
    int n = (b << 10) + hw;
    outq[m] = emb[(size_t)idx[n] * D_ + d];
}

// ---------------- one-hot encodings [N][K] as float4
__global__ __launch_bounds__(256) void vq_enc(const int* __restrict__ idx,
    f32x4* __restrict__ enc)
{
    size_t m = (size_t)blockIdx.x * 256 + threadIdx.x; // N*K/4 total
    int n = (int)(m >> 8);
    int k4 = (int)(m & 255) << 2;
    int kk = idx[n];
    f32x4 v;
    v[0] = (kk == k4) ? 1.f : 0.f;
    v[1] = (kk == k4 + 1) ? 1.f : 0.f;
    v[2] = (kk == k4 + 2) ? 1.f : 0.f;
    v[3] = (kk == k4 + 3) ? 1.f : 0.f;
    enc[m] = v;
}

// ---------------- finalize: loss scalar + perplexity
__global__ __launch_bounds__(256) void vq_fin(const int* __restrict__ counts,
    const double* __restrict__ loss_acc, float* __restrict__ d_out)
{
    int t = threadIdx.x;
    double s = 0.0;
    for (int k = t; k < K_; k += 256) {
        double p = (double)counts[k] / 32768.0;
        s += p * log(p + 1e-10);
    }
    for (int o = 32; o > 0; o >>= 1) s += __shfl_down(s, o);
    __shared__ double sred[4];
    if ((t & 63) == 0) sred[t >> 6] = s;
    __syncthreads();
    if (t == 0) {
        double tot = sred[0] + sred[1] + sred[2] + sred[3];
        d_out[0] = (float)(1.25 * (*loss_acc) / (double)QELEMS);
        d_out[8388609] = (float)exp(-tot);
    }
}

extern "C" void kernel_launch(void* const* d_in, const int* in_sizes, int n_in,
                              void* d_out, int out_size, void* d_ws, size_t ws_size,
                              hipStream_t stream)
{
    const float* x = (const float*)d_in[0];
    const float* emb = (const float*)d_in[1];
    char* ws = (char*)d_ws;
    unsigned short* ebf = (unsigned short*)(ws);                 // 512 KB
    float* enorm = (float*)(ws + 524288);                        // 4 KB
    int* idx = (int*)(ws + 528384);                              // 128 KB
    int* counts = (int*)(ws + 659456);                           // 4 KB
    double* lacc = (double*)(ws + 663552);                       // 8 B
    float* out = (float*)d_out;

    vq_prep<<<K_, 256, 0, stream>>>(emb, ebf, enorm, counts, lacc);
    vq_main<<<NROWS_ / 64, 512, 0, stream>>>(x, ebf, enorm, idx, counts, lacc);
    vq_scatter<<<QELEMS / 256, 256, 0, stream>>>(emb, idx, out + 1);
    vq_enc<<<(NROWS_ * (K_ / 4)) / 256, 256, 0, stream>>>(idx, (f32x4*)(out + 8388610));
    vq_fin<<<1, 256, 0, stream>>>(counts, lacc, out);
}

// Round 10
// 101.234 us; speedup vs baseline: 1.8706x; 1.8706x over previous
//
#include <hip/hip_runtime.h>
#include <hip/hip_bf16.h>

typedef short short8 __attribute__((ext_vector_type(8)));
typedef float f32x4 __attribute__((ext_vector_type(4)));
typedef unsigned short u16x4 __attribute__((ext_vector_type(4)));

#define D_ 256
#define K_ 1024
#define HW_ 1024
#define NROWS_ 32768
#define QELEMS 8388608  // 32*256*32*32

static __device__ __forceinline__ unsigned short to_bf16(float v) {
    __hip_bfloat16 h = __float2bfloat16(v);
    return *(unsigned short*)&h;
}

// ---------------- prep: emb -> bf16 codebook ebf[k][d], enorm[k]=sum e^2, zero counts/loss
__global__ __launch_bounds__(256) void vq_prep(const float* __restrict__ emb,
    unsigned short* __restrict__ ebf, float* __restrict__ enorm,
    int* __restrict__ counts, double* __restrict__ loss_acc)
{
    int k = blockIdx.x, t = threadIdx.x;           // k in [0,1024), t in [0,256)
    float v = emb[k * D_ + t];
    ebf[k * D_ + t] = to_bf16(v);
    float s = v * v;
    for (int o = 32; o > 0; o >>= 1) s += __shfl_down(s, o);
    __shared__ float ws4[4];
    if ((t & 63) == 0) ws4[t >> 6] = s;
    __syncthreads();
    if (t == 0) enorm[k] = ws4[0] + ws4[1] + ws4[2] + ws4[3];
    if (k < 4) counts[k * 256 + t] = 0;
    if (k == 0 && t == 0) *loss_acc = 0.0;
}

// ---------------- main: 64 rows/block, 8 waves, LDS-staged codebook chunks, top-1, fused loss
// wave w: rh=w&1 -> rows rh*32..+32 (2 tiles of 16); cq=w>>1 -> 16-code tile within 64-chunk
__global__ __launch_bounds__(512, 4) void vq_main(
    const float* __restrict__ x,
    const unsigned short* __restrict__ ebf, const float* __restrict__ enorm,
    int* __restrict__ idx, int* __restrict__ counts, double* __restrict__ loss_acc)
{
    __shared__ unsigned short xs[64 * 256];   // 32KB x tile, XOR-swizzled rows
    __shared__ unsigned short es[64 * 256];   // 32KB codebook chunk (swizzle-compensated src)
    __shared__ float xn[64][33];              // per-row |x|^2 partials
    __shared__ float ens[1024];               // enorm staged
    __shared__ float rminv[64][4];
    __shared__ int   rmini[64][4];

    const int t = threadIdx.x;
    const int n0 = blockIdx.x * 64;
    const int b = n0 >> 10;
    const int hw0 = n0 & 1023;
    const float* xbase = x + (size_t)b * (D_ * HW_) + hw0;

    ens[t] = enorm[t];
    ens[t + 512] = enorm[t + 512];

    // ---- stage x -> bf16 LDS: float4 loads along hw, 4x4 register transpose, b64 writes
    {
        const int rt = t & 15;          // row tile (rows 4rt..4rt+3)
        const int dg = t >> 4;          // 0..31
        const int r0 = rt * 4;
        float xp[4] = {0.f, 0.f, 0.f, 0.f};
#pragma unroll
        for (int m = 0; m < 2; ++m) {
            int d0 = (dg + 32 * m) * 4;
            f32x4 c[4];
#pragma unroll
            for (int q = 0; q < 4; ++q)
                c[q] = *(const f32x4*)(xbase + (size_t)(d0 + q) * HW_ + r0);
#pragma unroll
            for (int i = 0; i < 4; ++i) {
                u16x4 pk;
                pk[0] = to_bf16(c[0][i]); pk[1] = to_bf16(c[1][i]);
                pk[2] = to_bf16(c[2][i]); pk[3] = to_bf16(c[3][i]);
                xp[i] = fmaf(c[0][i], c[0][i], xp[i]);
                xp[i] = fmaf(c[1][i], c[1][i], xp[i]);
                xp[i] = fmaf(c[2][i], c[2][i], xp[i]);
                xp[i] = fmaf(c[3][i], c[3][i], xp[i]);
                int r = r0 + i;
                int byte = (r * 512 + d0 * 2) ^ ((r & 7) << 4);
                *(u16x4*)((char*)xs + byte) = pk;
            }
        }
#pragma unroll
        for (int i = 0; i < 4; ++i) xn[r0 + i][dg] = xp[i];
    }
    __syncthreads();

    const int lane = t & 63;
    const int w = t >> 6;          // wave 0..7
    const int rh = w & 1;          // row half (32 rows)
    const int cq = w >> 1;         // code quarter of each 64-chunk (16 codes)
    const int col = lane & 15;
    const int kg = lane >> 4;      // k-group 0..3

    // ---- A fragments: this wave's 32 rows (2 tiles of 16), whole kernel in registers
    short8 areg[2][8];
#pragma unroll
    for (int rt = 0; rt < 2; ++rt) {
        int row = rh * 32 + rt * 16 + col;
        int rowb = row * 512;
        int sw = (row & 7) << 4;
#pragma unroll
        for (int dc = 0; dc < 8; ++dc) {
            int byte = (rowb + dc * 64 + kg * 16) ^ sw;
            areg[rt][dc] = *(const short8*)((const char*)xs + byte);
        }
    }

    float v1[8]; int i1[8];
#pragma unroll
    for (int s = 0; s < 8; ++s) { v1[s] = 3.4e38f; i1[s] = 0x7fffffff; }

    const char* ebf_bytes = (const char*)ebf;
    char* es_bytes = (char*)es;
    const int wbyte = w * 4096;

    for (int cc = 0; cc < 16; ++cc) {
        // ---- stage chunk cc (codes cc*64..+64) -> es, coalesced, source pre-swizzled
        {
            const char* src = ebf_bytes + (size_t)cc * 32768;
#pragma unroll
            for (int j = 0; j < 4; ++j) {
                int p = wbyte + j * 1024 + lane * 16;         // linear LDS byte pos
                int q = p ^ (((p >> 9) & 7) << 4);            // inverse-swizzled source
                __builtin_amdgcn_global_load_lds(src + q, es_bytes + wbyte + j * 1024, 16, 0, 0);
            }
        }
        __syncthreads();   // drains vmcnt -> chunk resident for all waves

        // ---- 16 MFMAs: 2 row tiles x this wave's 16-code tile, K=256
        const int c0 = cq * 16 + col;                 // local code index
        const int sw0 = (c0 & 7) << 4;
        f32x4 acc0 = {0.f, 0.f, 0.f, 0.f};
        f32x4 acc1 = {0.f, 0.f, 0.f, 0.f};
#pragma unroll
        for (int dc = 0; dc < 8; ++dc) {
            short8 bf = *(const short8*)(es_bytes + ((c0 * 512 + dc * 64 + kg * 16) ^ sw0));
            acc0 = __builtin_amdgcn_mfma_f32_16x16x32_bf16(areg[0][dc], bf, acc0, 0, 0, 0);
            acc1 = __builtin_amdgcn_mfma_f32_16x16x32_bf16(areg[1][dc], bf, acc1, 0, 0, 0);
        }
        // dist = enorm - 2*dot ; C/D map: row=(lane>>4)*4+reg, col=lane&15
        {
            int code = cc * 64 + c0;
            float bn = ens[code];
#pragma unroll
            for (int r = 0; r < 4; ++r) {
                float dv = fmaf(-2.f, acc0[r], bn);
                if (dv < v1[r]) { v1[r] = dv; i1[r] = code; }
                float dw = fmaf(-2.f, acc1[r], bn);
                if (dw < v1[4 + r]) { v1[4 + r] = dw; i1[4 + r] = code; }
            }
        }
        __syncthreads();   // all waves done reading es before next overwrite
    }

    // ---- butterfly min over the 16 cols (lane bits 0-3), tie -> lower index
#pragma unroll
    for (int mask = 1; mask < 16; mask <<= 1) {
#pragma unroll
        for (int s = 0; s < 8; ++s) {
            float ov = __shfl_xor(v1[s], mask);
            int oi = __shfl_xor(i1[s], mask);
            if (ov < v1[s] || (ov == v1[s] && oi < i1[s])) { v1[s] = ov; i1[s] = oi; }
        }
    }
    if (col == 0) {
#pragma unroll
        for (int s = 0; s < 8; ++s) {
            int rt = s >> 2, r = s & 3;
            int row = rh * 32 + rt * 16 + kg * 4 + r;
            rminv[row][cq] = v1[s];
            rmini[row][cq] = i1[s];
        }
    }
    __syncthreads();

    // ---- finalize (wave 0): pick across 4 code quarters, idx/counts/loss
    if (t < 64) {
        float dmin = rminv[t][0]; int best = rmini[t][0];
#pragma unroll
        for (int g = 1; g < 4; ++g) {
            float cv = rminv[t][g]; int ci = rmini[t][g];
            if (cv < dmin || (cv == dmin && ci < best)) { dmin = cv; best = ci; }
        }
        idx[n0 + t] = best;
        atomicAdd(&counts[best], 1);
        float s = 0.f;
#pragma unroll 8
        for (int g = 0; g < 32; ++g) s += xn[t][g];
        float lrow = dmin + s;     // |x-e|^2 = (|e|^2 - 2x.e) + |x|^2
        for (int o = 32; o > 0; o >>= 1) lrow += __shfl_down(lrow, o);
        if (t == 0) atomicAdd(loss_acc, (double)lrow);
    }
}

// ---------------- scatter quantized (BCHW): out[b][d][hw] = emb[idx[b*1024+hw]][d]
__global__ __launch_bounds__(256) void vq_scatter(const float* __restrict__ emb,
    const int* __restrict__ idx, float* __restrict__ outq)
{
    size_t m = (size_t)blockIdx.x * 256 + threadIdx.x;
    int hw = (int)(m & 1023);
    int d = (int)((m >> 10) & 255);
    int b = (int)(m >> 18);
    int n = (b << 10) + hw;
    outq[m] = emb[(size_t)idx[n] * D_ + d];
}

// ---------------- one-hot encodings [N][K] as float2 (8B-aligned at out+8388610)
__global__ __launch_bounds__(256) void vq_enc(const int* __restrict__ idx,
    float2* __restrict__ enc)
{
    size_t m = (size_t)blockIdx.x * 256 + threadIdx.x; // N*K/2 total
    int n = (int)(m >> 9);
    int k2 = (int)(m & 511) << 1;
    int kk = idx[n];
    float2 v;
    v.x = (kk == k2) ? 1.f : 0.f;
    v.y = (kk == k2 + 1) ? 1.f : 0.f;
    enc[m] = v;
}

// ---------------- finalize: loss scalar + perplexity
__global__ __launch_bounds__(256) void vq_fin(const int* __restrict__ counts,
    const double* __restrict__ loss_acc, float* __restrict__ d_out)
{
    int t = threadIdx.x;
    double s = 0.0;
    for (int k = t; k < K_; k += 256) {
        double p = (double)counts[k] / 32768.0;
        s += p * log(p + 1e-10);
    }
    for (int o = 32; o > 0; o >>= 1) s += __shfl_down(s, o);
    __shared__ double sred[4];
    if ((t & 63) == 0) sred[t >> 6] = s;
    __syncthreads();
    if (t == 0) {
        double tot = sred[0] + sred[1] + sred[2] + sred[3];
        d_out[0] = (float)(1.25 * (*loss_acc) / (double)QELEMS);
        d_out[8388609] = (float)exp(-tot);
    }
}

extern "C" void kernel_launch(void* const* d_in, const int* in_sizes, int n_in,
                              void* d_out, int out_size, void* d_ws, size_t ws_size,
                              hipStream_t stream)
{
    const float* x = (const float*)d_in[0];
    const float* emb = (const float*)d_in[1];
    char* ws = (char*)d_ws;
    unsigned short* ebf = (unsigned short*)(ws);                 // 512 KB
    float* enorm = (float*)(ws + 524288);                        // 4 KB
    int* idx = (int*)(ws + 528384);                              // 128 KB
    int* counts = (int*)(ws + 659456);                           // 4 KB
    double* lacc = (double*)(ws + 663552);                       // 8 B
    float* out = (float*)d_out;

    vq_prep<<<K_, 256, 0, stream>>>(emb, ebf, enorm, counts, lacc);
    vq_main<<<NROWS_ / 64, 512, 0, stream>>>(x, ebf, enorm, idx, counts, lacc);
    vq_scatter<<<QELEMS / 256, 256, 0, stream>>>(emb, idx, out + 1);
    vq_enc<<<(NROWS_ * (K_ / 2)) / 256, 256, 0, stream>>>(idx, (float2*)(out + 8388610));
    vq_fin<<<1, 256, 0, stream>>>(counts, lacc, out);
}

// Round 11
// 70.241 us; speedup vs baseline: 2.6960x; 1.4412x over previous
//
#include <hip/hip_runtime.h>
#include <hip/hip_bf16.h>

typedef short short8 __attribute__((ext_vector_type(8)));
typedef float f32x4 __attribute__((ext_vector_type(4)));
typedef unsigned short u16x4 __attribute__((ext_vector_type(4)));

#define D_ 256
#define K_ 1024
#define HW_ 1024
#define NROWS_ 32768
#define QELEMS 8388608  // 32*256*32*32

static __device__ __forceinline__ unsigned short to_bf16(float v) {
    __hip_bfloat16 h = __float2bfloat16(v);
    return *(unsigned short*)&h;
}

// ---------------- prep: emb -> bf16 codebook ebf[k][d], enorm[k]=sum e^2, zero counts/loss
__global__ __launch_bounds__(256) void vq_prep(const float* __restrict__ emb,
    unsigned short* __restrict__ ebf, float* __restrict__ enorm,
    int* __restrict__ counts, double* __restrict__ loss_acc)
{
    int k = blockIdx.x, t = threadIdx.x;           // k in [0,1024), t in [0,256)
    float v = emb[k * D_ + t];
    ebf[k * D_ + t] = to_bf16(v);
    float s = v * v;
    for (int o = 32; o > 0; o >>= 1) s += __shfl_down(s, o);
    __shared__ float ws4[4];
    if ((t & 63) == 0) ws4[t >> 6] = s;
    __syncthreads();
    if (t == 0) enorm[k] = ws4[0] + ws4[1] + ws4[2] + ws4[3];
    if (k < 4) counts[k * 256 + t] = 0;
    if (k == 0 && t == 0) *loss_acc = 0.0;
}

// ---------------- main: 64 rows/block, 8 waves. Ping-pong LDS codebook staging, MFMA argmin,
// fused loss + quantized scatter + one-hot encodings. 3-kernel pipeline total.
__global__ __launch_bounds__(512, 4) void vq_main(
    const float* __restrict__ x, const float* __restrict__ emb,
    const unsigned short* __restrict__ ebf, const float* __restrict__ enorm,
    int* __restrict__ counts, double* __restrict__ loss_acc, float* __restrict__ out)
{
    // union: [xs 32K | es half0 32K..] overlapped later by q_lds [64][65] float4 = 66560 B
    __shared__ char smem[66560];
    __shared__ float xn[64][33];              // per-row |x|^2 partials
    __shared__ float rminv[64][4];
    __shared__ int   rmini[64][4];
    __shared__ int   bestsh[64];

    unsigned short* xs = (unsigned short*)smem;   // [0, 32K) during x-stage
    char* es = smem;                              // chunk halves at +0 / +32768

    const int t = threadIdx.x;
    const int n0 = blockIdx.x * 64;
    const int b = n0 >> 10;
    const int hw0 = n0 & 1023;
    const float* xbase = x + (size_t)b * (D_ * HW_) + hw0;

    // ---- stage x -> bf16 LDS: float4 loads along hw, 4x4 register transpose, b64 writes
    {
        const int rt = t & 15;          // rows 4rt..4rt+3
        const int dg = t >> 4;          // 0..31
        const int r0 = rt * 4;
        float xp[4] = {0.f, 0.f, 0.f, 0.f};
#pragma unroll
        for (int m = 0; m < 2; ++m) {
            int d0 = (dg + 32 * m) * 4;
            f32x4 c[4];
#pragma unroll
            for (int q = 0; q < 4; ++q)
                c[q] = *(const f32x4*)(xbase + (size_t)(d0 + q) * HW_ + r0);
#pragma unroll
            for (int i = 0; i < 4; ++i) {
                u16x4 pk;
                pk[0] = to_bf16(c[0][i]); pk[1] = to_bf16(c[1][i]);
                pk[2] = to_bf16(c[2][i]); pk[3] = to_bf16(c[3][i]);
                xp[i] = fmaf(c[0][i], c[0][i], xp[i]);
                xp[i] = fmaf(c[1][i], c[1][i], xp[i]);
                xp[i] = fmaf(c[2][i], c[2][i], xp[i]);
                xp[i] = fmaf(c[3][i], c[3][i], xp[i]);
                int r = r0 + i;
                int byte = (r * 512 + d0 * 2) ^ ((r & 7) << 4);
                *(u16x4*)((char*)xs + byte) = pk;
            }
        }
#pragma unroll
        for (int i = 0; i < 4; ++i) xn[r0 + i][dg] = xp[i];
    }
    __syncthreads();

    const int lane = t & 63;
    const int w = t >> 6;          // wave 0..7
    const int rh = w & 1;          // row half (32 rows)
    const int cq = w >> 1;         // 16-code tile within 64-chunk
    const int col = lane & 15;
    const int kg = lane >> 4;      // k-group 0..3
    const char* ebf_bytes = (const char*)ebf;
    const int wbyte = w * 4096;

    // ---- prologue: issue stage of chunk 0 -> half1 (doesn't touch xs)
    {
#pragma unroll
        for (int j = 0; j < 4; ++j) {
            int p = wbyte + j * 1024 + lane * 16;
            int qq = p ^ (((p >> 9) & 7) << 4);     // inverse-swizzled source
            __builtin_amdgcn_global_load_lds(ebf_bytes + qq, es + 32768 + wbyte + j * 1024, 16, 0, 0);
        }
    }

    // ---- A fragments: this wave's 32 rows (2 tiles of 16), whole kernel in registers
    short8 areg[2][8];
#pragma unroll
    for (int rt = 0; rt < 2; ++rt) {
        int row = rh * 32 + rt * 16 + col;
        int rowb = row * 512;
        int sw = (row & 7) << 4;
#pragma unroll
        for (int dc = 0; dc < 8; ++dc) {
            int byte = (rowb + dc * 64 + kg * 16) ^ sw;
            areg[rt][dc] = *(const short8*)((const char*)xs + byte);
        }
    }

    float v1[8]; int i1[8];
#pragma unroll
    for (int s = 0; s < 8; ++s) { v1[s] = 3.4e38f; i1[s] = 0x7fffffff; }

    for (int cc = 0; cc < 16; ++cc) {
        __syncthreads();   // chunk cc resident; all waves done with the half we stage next
        const int hc = ((cc & 1) ^ 1) * 32768;
        if (cc < 15) {     // issue next-chunk stage into other half; overlaps compute below
            const char* src = ebf_bytes + (size_t)(cc + 1) * 32768;
            const int hn = (cc & 1) * 32768;
#pragma unroll
            for (int j = 0; j < 4; ++j) {
                int p = wbyte + j * 1024 + lane * 16;
                int qq = p ^ (((p >> 9) & 7) << 4);
                __builtin_amdgcn_global_load_lds(src + qq, es + hn + wbyte + j * 1024, 16, 0, 0);
            }
        }
        const int c0 = cq * 16 + col;
        const int sw0 = (c0 & 7) << 4;
        f32x4 acc0 = {0.f, 0.f, 0.f, 0.f};
        f32x4 acc1 = {0.f, 0.f, 0.f, 0.f};
#pragma unroll
        for (int dc = 0; dc < 8; ++dc) {
            short8 bf = *(const short8*)(es + hc + ((c0 * 512 + dc * 64 + kg * 16) ^ sw0));
            acc0 = __builtin_amdgcn_mfma_f32_16x16x32_bf16(areg[0][dc], bf, acc0, 0, 0, 0);
            acc1 = __builtin_amdgcn_mfma_f32_16x16x32_bf16(areg[1][dc], bf, acc1, 0, 0, 0);
        }
        int code = cc * 64 + c0;
        float bn = enorm[code];   // L1-cached
#pragma unroll
        for (int r = 0; r < 4; ++r) {
            float dv = fmaf(-2.f, acc0[r], bn);
            if (dv < v1[r]) { v1[r] = dv; i1[r] = code; }
            float dw = fmaf(-2.f, acc1[r], bn);
            if (dw < v1[4 + r]) { v1[4 + r] = dw; i1[4 + r] = code; }
        }
    }

    // ---- butterfly min over 16 cols (lane bits 0-3), tie -> lower index
#pragma unroll
    for (int mask = 1; mask < 16; mask <<= 1) {
#pragma unroll
        for (int s = 0; s < 8; ++s) {
            float ov = __shfl_xor(v1[s], mask);
            int oi = __shfl_xor(i1[s], mask);
            if (ov < v1[s] || (ov == v1[s] && oi < i1[s])) { v1[s] = ov; i1[s] = oi; }
        }
    }
    if (col == 0) {
#pragma unroll
        for (int s = 0; s < 8; ++s) {
            int rt = s >> 2, r = s & 3;
            int row = rh * 32 + rt * 16 + kg * 4 + r;
            rminv[row][cq] = v1[s];
            rmini[row][cq] = i1[s];
        }
    }
    __syncthreads();   // also gates: all waves finished reading es before smem reuse

    // ---- finalize (wave 0): pick across 4 code tiles, counts/loss/bestsh
    if (t < 64) {
        float dmin = rminv[t][0]; int best = rmini[t][0];
#pragma unroll
        for (int g = 1; g < 4; ++g) {
            float cv = rminv[t][g]; int ci = rmini[t][g];
            if (cv < dmin || (cv == dmin && ci < best)) { dmin = cv; best = ci; }
        }
        bestsh[t] = best;
        atomicAdd(&counts[best], 1);
        float s = 0.f;
#pragma unroll 8
        for (int g = 0; g < 32; ++g) s += xn[t][g];
        float lrow = dmin + s;     // |x-e|^2 = (|e|^2 - 2x.e) + |x|^2
        for (int o = 32; o > 0; o >>= 1) lrow += __shfl_down(lrow, o);
        if (t == 0) atomicAdd(loss_acc, (double)lrow);
    }
    __syncthreads();

    // ---- gather chosen fp32 codebook rows coalesced into q_lds [64][65] float4
    {
        int r = w * 8 + (lane & 7);          // row within tile
        int c = lane >> 3;                   // 0..7: 32-float segment
        const f32x4* src4 = (const f32x4*)emb + (size_t)bestsh[r] * 64 + c * 8;
        f32x4* dst4 = (f32x4*)smem + r * 65 + c * 8;
#pragma unroll
        for (int j = 0; j < 8; ++j) dst4[j] = src4[j];
    }
    __syncthreads();

    // ---- write quantized out[b][d][hw0+hwr] (wave = 256B contiguous per d)
    {
        const int hwr = t & 63;
        const int dq = t >> 6;               // 0..7
        float* outq = out + 1 + (size_t)b * (D_ * HW_) + hw0 + hwr;
        const float* qrow = (const float*)smem + hwr * 260;
#pragma unroll
        for (int dd = 0; dd < 32; ++dd) {
            int d = dq + dd * 8;
            outq[(size_t)d * HW_] = qrow[d];
        }
    }
    // ---- encodings: zero-stream 8 rows per wave (512B contiguous per instr), then poke 1.0
    {
        float2* ez = (float2*)(out + 8388610 + (size_t)(n0 + w * 8) * 1024);
        float2 zz; zz.x = 0.f; zz.y = 0.f;
#pragma unroll 8
        for (int j = 0; j < 64; ++j) ez[j * 64 + lane] = zz;
    }
    __syncthreads();
    if (t < 64) out[8388610 + (size_t)(n0 + t) * 1024 + bestsh[t]] = 1.0f;
}

// ---------------- finalize: loss scalar + perplexity
__global__ __launch_bounds__(256) void vq_fin(const int* __restrict__ counts,
    const double* __restrict__ loss_acc, float* __restrict__ d_out)
{
    int t = threadIdx.x;
    double s = 0.0;
    for (int k = t; k < K_; k += 256) {
        double p = (double)counts[k] / 32768.0;
        s += p * log(p + 1e-10);
    }
    for (int o = 32; o > 0; o >>= 1) s += __shfl_down(s, o);
    __shared__ double sred[4];
    if ((t & 63) == 0) sred[t >> 6] = s;
    __syncthreads();
    if (t == 0) {
        double tot = sred[0] + sred[1] + sred[2] + sred[3];
        d_out[0] = (float)(1.25 * (*loss_acc) / (double)QELEMS);
        d_out[8388609] = (float)exp(-tot);
    }
}

extern "C" void kernel_launch(void* const* d_in, const int* in_sizes, int n_in,
                              void* d_out, int out_size, void* d_ws, size_t ws_size,
                              hipStream_t stream)
{
    const float* x = (const float*)d_in[0];
    const float* emb = (const float*)d_in[1];
    char* ws = (char*)d_ws;
    unsigned short* ebf = (unsigned short*)(ws);                 // 512 KB
    float* enorm = (float*)(ws + 524288);                        // 4 KB
    int* counts = (int*)(ws + 528384);                           // 4 KB
    double* lacc = (double*)(ws + 532480);                       // 8 B
    float* out = (float*)d_out;

    vq_prep<<<K_, 256, 0, stream>>>(emb, ebf, enorm, counts, lacc);
    vq_main<<<NROWS_ / 64, 512, 0, stream>>>(x, emb, ebf, enorm, counts, lacc, out);
    vq_fin<<<1, 256, 0, stream>>>(counts, lacc, out);
}